// Round 2
// baseline (876.579 us; speedup 1.0000x reference)
//
#include <hip/hip_runtime.h>
#include <hip/hip_bf16.h>

#define N_NODES 50000
#define N_EDGES 1600000
#define HEADS 8
#define HD 32
#define FIN 256
#define HID 256

typedef unsigned short u16;
typedef unsigned int u32;

__device__ __forceinline__ float bf2f(u16 v) {
  union { u32 u; float f; } c; c.u = ((u32)v) << 16; return c.f;
}
__device__ __forceinline__ u16 f2bf(float f) {
  union { u32 u; float f; } c; c.f = f;
  u32 u = c.u;
  return (u16)((u + 0x7FFFu + ((u >> 16) & 1u)) >> 16);  // RNE
}

// ---------------- GEMM: H[n][h*32+d] = X[n,:] @ W[h,:,d] + bw[h,d] ----------
// fp32 inputs. Block: 256 threads, tile 64 nodes x 64 outputs, K-tiles of 64.
// Hb stored as bf16 to halve gather traffic in k_fused (2% threshold permits).
__global__ __launch_bounds__(256) void k_gemm(
    const float* __restrict__ X, const float* __restrict__ W,
    const float* __restrict__ bw, u16* __restrict__ Hb) {
  __shared__ float Xs[64][68];   // +4 pad: 16B-aligned rows, breaks bank conflicts
  __shared__ float Ws[64][64];
  const int t = threadIdx.x;
  const int m0 = (blockIdx.x >> 2) * 64;
  const int n0 = (blockIdx.x & 3) * 64;
  const int tn = t & 15, ti = t >> 4;
  float acc[4][4] = {{0.f}};
  for (int k0 = 0; k0 < FIN; k0 += 64) {
#pragma unroll
    for (int r = 0; r < 16; r++) {
      int idx = (r << 8) + t;
      int kk = idx & 63, i = idx >> 6;
      int node = m0 + i;
      Xs[kk][i] = (node < N_NODES) ? X[node * FIN + k0 + kk] : 0.f;
    }
#pragma unroll
    for (int r = 0; r < 16; r++) {
      int idx = (r << 8) + t;
      int nn = idx & 63, kk = idx >> 6;
      int n = n0 + nn;
      int h = n >> 5, d = n & 31;
      Ws[kk][nn] = W[h * (FIN * HD) + (k0 + kk) * HD + d];
    }
    __syncthreads();
#pragma unroll 8
    for (int kk = 0; kk < 64; kk++) {
      const float4 xv = *(const float4*)&Xs[kk][ti << 2];
      const float4 wv = *(const float4*)&Ws[kk][tn << 2];
      acc[0][0] += xv.x * wv.x; acc[0][1] += xv.x * wv.y; acc[0][2] += xv.x * wv.z; acc[0][3] += xv.x * wv.w;
      acc[1][0] += xv.y * wv.x; acc[1][1] += xv.y * wv.y; acc[1][2] += xv.y * wv.z; acc[1][3] += xv.y * wv.w;
      acc[2][0] += xv.z * wv.x; acc[2][1] += xv.z * wv.y; acc[2][2] += xv.z * wv.z; acc[2][3] += xv.z * wv.w;
      acc[3][0] += xv.w * wv.x; acc[3][1] += xv.w * wv.y; acc[3][2] += xv.w * wv.z; acc[3][3] += xv.w * wv.w;
    }
    __syncthreads();
  }
  const int nbase = n0 + (tn << 2);
#pragma unroll
  for (int i = 0; i < 4; i++) {
    int node = m0 + (ti << 2) + i;
    if (node < N_NODES) {
      ushort4 o;
      o.x = f2bf(acc[i][0] + bw[nbase + 0]);
      o.y = f2bf(acc[i][1] + bw[nbase + 1]);
      o.z = f2bf(acc[i][2] + bw[nbase + 2]);
      o.w = f2bf(acc[i][3] + bw[nbase + 3]);
      *(ushort4*)&Hb[node * HID + nbase] = o;
    }
  }
}

// ---------------- attention projections si = h.a1, sj = h.a2 ----------------
__global__ __launch_bounds__(256) void k_attn(
    const u16* __restrict__ Hb, const float* __restrict__ A,
    float* __restrict__ si, float* __restrict__ sj) {
  const int n = blockIdx.x;
  const int t = threadIdx.x;
  const int h = t >> 5, d = t & 31;
  float hv = bf2f(Hb[n * HID + t]);
  float s1 = hv * A[h * 64 + d];
  float s2 = hv * A[h * 64 + 32 + d];
#pragma unroll
  for (int off = 16; off >= 1; off >>= 1) {
    s1 += __shfl_xor(s1, off);
    s2 += __shfl_xor(s2, off);
  }
  if (d == 0) { si[n * HEADS + h] = s1; sj[n * HEADS + h] = s2; }
}

// ---------------- counting sort of edges by target ----------------
__global__ void k_hist(const int* __restrict__ tgt, int* __restrict__ cnt) {
  int e = blockIdx.x * 256 + threadIdx.x;
  if (e < N_EDGES) atomicAdd(&cnt[tgt[e]], 1);
}

__global__ __launch_bounds__(256) void k_scan1(const int* __restrict__ cnt,
    int* __restrict__ excl, int* __restrict__ bsum) {
  __shared__ int s[256];
  const int t = threadIdx.x;
  const int i = blockIdx.x * 256 + t;
  int v = (i < N_NODES) ? cnt[i] : 0;
  s[t] = v;
  __syncthreads();
  int x = v;
  for (int off = 1; off < 256; off <<= 1) {
    int y = (t >= off) ? s[t - off] : 0;
    __syncthreads();
    x += y;
    s[t] = x;
    __syncthreads();
  }
  if (i < N_NODES) excl[i] = x - v;
  if (t == 255) bsum[blockIdx.x] = x;
}

__global__ __launch_bounds__(256) void k_scan2(const int* __restrict__ bsum,
                                               int* __restrict__ boff) {
  __shared__ int s[256];
  const int t = threadIdx.x;
  int v = (t < 196) ? bsum[t] : 0;
  s[t] = v;
  __syncthreads();
  int x = v;
  for (int off = 1; off < 256; off <<= 1) {
    int y = (t >= off) ? s[t - off] : 0;
    __syncthreads();
    x += y;
    s[t] = x;
    __syncthreads();
  }
  if (t < 196) boff[t] = x - v;
}

__global__ void k_scan3(const int* __restrict__ excl, const int* __restrict__ boff,
                        int* __restrict__ rowptr, int* __restrict__ cursor) {
  int i = blockIdx.x * 256 + threadIdx.x;
  if (i < N_NODES) {
    int v = excl[i] + boff[blockIdx.x];
    rowptr[i] = v;
    cursor[i] = v;
  }
}

__global__ void k_scatter(const int* __restrict__ tgt, const int* __restrict__ src,
                          int* __restrict__ cursor, int* __restrict__ sortedSrc) {
  int e = blockIdx.x * 256 + threadIdx.x;
  if (e < N_EDGES) {
    int tg = tgt[e];
    int pos = atomicAdd(&cursor[tg], 1);
    sortedSrc[pos] = src[e];
  }
}

// ---------------- fused: softmax-agg + skip + ELU + LN + head-mean + Wout + ELU
__global__ __launch_bounds__(256) void k_fused(
    const u16* __restrict__ Hb, const float* __restrict__ si,
    const float* __restrict__ sj, const float* __restrict__ ba,
    const float* __restrict__ gamma, const float* __restrict__ beta,
    const float* __restrict__ Wout, const float* __restrict__ bout,
    const int* __restrict__ rowptr, const int* __restrict__ cnt,
    const int* __restrict__ sortedSrc, float* __restrict__ out) {
  __shared__ float lds[256];
  __shared__ float meanv[32];
  const int n = blockIdx.x;
  const int t = threadIdx.x;
  const int h = t >> 5;
  const int start = rowptr[n];
  const int deg = cnt[n];
  const float bah = ba[h];
  const float sit = si[n * HEADS + h];
  float acc = 0.f, den = 0.f;
  for (int i2 = 0; i2 < deg; i2++) {
    int s = sortedSrc[start + i2];
    float e = sit + sj[s * HEADS + h] + bah;
    e = (e >= 0.f) ? e : 0.2f * e;
    float ex = __expf(e);
    den += ex;
    acc += ex * bf2f(Hb[s * HID + t]);
  }
  float hs = bf2f(Hb[n * HID + t]);
  float v = ((deg > 0) ? (acc / den) : 0.f) + hs;
  v = (v > 0.f) ? v : expm1f(v);
  // LayerNorm over the 32 lanes of this head
  float sum = v, sq = v * v;
#pragma unroll
  for (int off = 16; off >= 1; off >>= 1) {
    sum += __shfl_xor(sum, off);
    sq  += __shfl_xor(sq, off);
  }
  float mu = sum * (1.f / 32.f);
  float var = sq * (1.f / 32.f) - mu * mu;
  float nv = (v - mu) * rsqrtf(var + 1e-5f) * gamma[t] + beta[t];
  lds[t] = nv;
  __syncthreads();
  if (t < 32) {
    float m2 = 0.f;
#pragma unroll
    for (int hh = 0; hh < HEADS; hh++) m2 += lds[hh * 32 + t];
    meanv[t] = m2 * 0.125f;
  }
  __syncthreads();
  float y = bout[t];
#pragma unroll
  for (int k = 0; k < 32; k++) y += meanv[k] * Wout[k * HID + t];
  y = (y > 0.f) ? y : expm1f(y);
  out[n * HID + t] = y;
}

extern "C" void kernel_launch(void* const* d_in, const int* in_sizes, int n_in,
                              void* d_out, int out_size, void* d_ws, size_t ws_size,
                              hipStream_t stream) {
  const float* X     = (const float*)d_in[0];
  const int*   EI    = (const int*)d_in[1];
  const float* W     = (const float*)d_in[2];
  const float* bw    = (const float*)d_in[3];
  const float* A     = (const float*)d_in[4];
  const float* ba    = (const float*)d_in[5];
  const float* gamma = (const float*)d_in[6];
  const float* beta  = (const float*)d_in[7];
  const float* Wout  = (const float*)d_in[8];
  const float* bout  = (const float*)d_in[9];
  float* out = (float*)d_out;
  const int* tgt = EI;
  const int* src = EI + N_EDGES;

  char* ws = (char*)d_ws;
  size_t off = 0;
  auto alloc = [&](size_t bytes) -> void* {
    void* p = ws + off;
    off += bytes;
    off = (off + 255) & ~(size_t)255;
    return p;
  };
  u16*   Hb        = (u16*)  alloc((size_t)N_NODES * HID * 2);
  float* si        = (float*)alloc((size_t)N_NODES * HEADS * 4);
  float* sj        = (float*)alloc((size_t)N_NODES * HEADS * 4);
  int*   cnt       = (int*)  alloc((size_t)N_NODES * 4);
  int*   excl      = (int*)  alloc((size_t)N_NODES * 4);
  int*   bsum      = (int*)  alloc(256 * 4);
  int*   boff      = (int*)  alloc(256 * 4);
  int*   rowptr    = (int*)  alloc((size_t)N_NODES * 4);
  int*   cursor    = (int*)  alloc((size_t)N_NODES * 4);
  int*   sortedSrc = (int*)  alloc((size_t)N_EDGES * 4);

  hipMemsetAsync(cnt, 0, (size_t)N_NODES * 4, stream);
  k_hist<<<(N_EDGES + 255) / 256, 256, 0, stream>>>(tgt, cnt);
  k_scan1<<<196, 256, 0, stream>>>(cnt, excl, bsum);
  k_scan2<<<1, 256, 0, stream>>>(bsum, boff);
  k_scan3<<<196, 256, 0, stream>>>(excl, boff, rowptr, cursor);
  k_scatter<<<(N_EDGES + 255) / 256, 256, 0, stream>>>(tgt, src, cursor, sortedSrc);
  k_gemm<<<((N_NODES + 63) / 64) * 4, 256, 0, stream>>>(X, W, bw, Hb);
  k_attn<<<N_NODES, 256, 0, stream>>>(Hb, A, si, sj);
  k_fused<<<N_NODES, 256, 0, stream>>>(Hb, si, sj, ba, gamma, beta, Wout, bout,
                                       rowptr, cnt, sortedSrc, out);
}

// Round 3
// 758.314 us; speedup vs baseline: 1.1560x; 1.1560x over previous
//
#include <hip/hip_runtime.h>
#include <hip/hip_bf16.h>

#define N_NODES 50000
#define N_EDGES 1600000
#define HEADS 8
#define HD 32
#define FIN 256
#define HID 256

typedef unsigned short u16;
typedef unsigned int u32;

__device__ __forceinline__ float bf2f(u16 v) {
  union { u32 u; float f; } c; c.u = ((u32)v) << 16; return c.f;
}
__device__ __forceinline__ u16 f2bf(float f) {
  union { u32 u; float f; } c; c.f = f;
  u32 u = c.u;
  return (u16)((u + 0x7FFFu + ((u >> 16) & 1u)) >> 16);  // RNE
}

// ---------------- GEMM: H[n][h*32+d] = X[n,:] @ W[h,:,d] + bw[h,d] ----------
__global__ __launch_bounds__(256) void k_gemm(
    const float* __restrict__ X, const float* __restrict__ W,
    const float* __restrict__ bw, u16* __restrict__ Hb) {
  __shared__ float Xs[64][68];
  __shared__ float Ws[64][64];
  const int t = threadIdx.x;
  const int m0 = (blockIdx.x >> 2) * 64;
  const int n0 = (blockIdx.x & 3) * 64;
  const int tn = t & 15, ti = t >> 4;
  float acc[4][4] = {{0.f}};
  for (int k0 = 0; k0 < FIN; k0 += 64) {
#pragma unroll
    for (int r = 0; r < 16; r++) {
      int idx = (r << 8) + t;
      int kk = idx & 63, i = idx >> 6;
      int node = m0 + i;
      Xs[kk][i] = (node < N_NODES) ? X[node * FIN + k0 + kk] : 0.f;
    }
#pragma unroll
    for (int r = 0; r < 16; r++) {
      int idx = (r << 8) + t;
      int nn = idx & 63, kk = idx >> 6;
      int n = n0 + nn;
      int h = n >> 5, d = n & 31;
      Ws[kk][nn] = W[h * (FIN * HD) + (k0 + kk) * HD + d];
    }
    __syncthreads();
#pragma unroll 8
    for (int kk = 0; kk < 64; kk++) {
      const float4 xv = *(const float4*)&Xs[kk][ti << 2];
      const float4 wv = *(const float4*)&Ws[kk][tn << 2];
      acc[0][0] += xv.x * wv.x; acc[0][1] += xv.x * wv.y; acc[0][2] += xv.x * wv.z; acc[0][3] += xv.x * wv.w;
      acc[1][0] += xv.y * wv.x; acc[1][1] += xv.y * wv.y; acc[1][2] += xv.y * wv.z; acc[1][3] += xv.y * wv.w;
      acc[2][0] += xv.z * wv.x; acc[2][1] += xv.z * wv.y; acc[2][2] += xv.z * wv.z; acc[2][3] += xv.z * wv.w;
      acc[3][0] += xv.w * wv.x; acc[3][1] += xv.w * wv.y; acc[3][2] += xv.w * wv.z; acc[3][3] += xv.w * wv.w;
    }
    __syncthreads();
  }
  const int nbase = n0 + (tn << 2);
#pragma unroll
  for (int i = 0; i < 4; i++) {
    int node = m0 + (ti << 2) + i;
    if (node < N_NODES) {
      ushort4 o;
      o.x = f2bf(acc[i][0] + bw[nbase + 0]);
      o.y = f2bf(acc[i][1] + bw[nbase + 1]);
      o.z = f2bf(acc[i][2] + bw[nbase + 2]);
      o.w = f2bf(acc[i][3] + bw[nbase + 3]);
      *(ushort4*)&Hb[node * HID + nbase] = o;
    }
  }
}

// ---------------- attention projections si = h.a1, sj = h.a2 ----------------
__global__ __launch_bounds__(256) void k_attn(
    const u16* __restrict__ Hb, const float* __restrict__ A,
    float* __restrict__ si, float* __restrict__ sj) {
  const int n = blockIdx.x;
  const int t = threadIdx.x;
  const int h = t >> 5, d = t & 31;
  float hv = bf2f(Hb[n * HID + t]);
  float s1 = hv * A[h * 64 + d];
  float s2 = hv * A[h * 64 + 32 + d];
#pragma unroll
  for (int off = 16; off >= 1; off >>= 1) {
    s1 += __shfl_xor(s1, off);
    s2 += __shfl_xor(s2, off);
  }
  if (d == 0) { si[n * HEADS + h] = s1; sj[n * HEADS + h] = s2; }
}

// ---------------- counting sort of edges by target ----------------
__global__ void k_hist(const int* __restrict__ tgt, int* __restrict__ cnt) {
  int e = blockIdx.x * 256 + threadIdx.x;
  if (e < N_EDGES) atomicAdd(&cnt[tgt[e]], 1);
}

__global__ __launch_bounds__(256) void k_scan1(const int* __restrict__ cnt,
    int* __restrict__ excl, int* __restrict__ bsum) {
  __shared__ int s[256];
  const int t = threadIdx.x;
  const int i = blockIdx.x * 256 + t;
  int v = (i < N_NODES) ? cnt[i] : 0;
  s[t] = v;
  __syncthreads();
  int x = v;
  for (int off = 1; off < 256; off <<= 1) {
    int y = (t >= off) ? s[t - off] : 0;
    __syncthreads();
    x += y;
    s[t] = x;
    __syncthreads();
  }
  if (i < N_NODES) excl[i] = x - v;
  if (t == 255) bsum[blockIdx.x] = x;
}

__global__ __launch_bounds__(256) void k_scan2(const int* __restrict__ bsum,
                                               int* __restrict__ boff) {
  __shared__ int s[256];
  const int t = threadIdx.x;
  int v = (t < 196) ? bsum[t] : 0;
  s[t] = v;
  __syncthreads();
  int x = v;
  for (int off = 1; off < 256; off <<= 1) {
    int y = (t >= off) ? s[t - off] : 0;
    __syncthreads();
    x += y;
    s[t] = x;
    __syncthreads();
  }
  if (t < 196) boff[t] = x - v;
}

__global__ void k_scan3(const int* __restrict__ excl, const int* __restrict__ boff,
                        int* __restrict__ rowptr, int* __restrict__ cursor) {
  int i = blockIdx.x * 256 + threadIdx.x;
  if (i < N_NODES) {
    int v = excl[i] + boff[blockIdx.x];
    rowptr[i] = v;
    cursor[i] = v;
  }
}

__global__ void k_scatter(const int* __restrict__ tgt, const int* __restrict__ src,
                          int* __restrict__ cursor, int* __restrict__ sortedSrc) {
  int e = blockIdx.x * 256 + threadIdx.x;
  if (e < N_EDGES) {
    int tg = tgt[e];
    int pos = atomicAdd(&cursor[tg], 1);
    sortedSrc[pos] = src[e];
  }
}

// ---------------- fused: softmax-agg + skip + ELU + LN + head-mean + Wout + ELU
// Phase A: 32 edges x 8 heads in parallel -> exp scores staged in LDS (each exp once).
// Phase B: 2 cols/thread (dword bf16x2 gather), 2 edges per block-iteration.
__global__ __launch_bounds__(256) void k_fused(
    const u16* __restrict__ Hb, const float* __restrict__ si,
    const float* __restrict__ sj, const float* __restrict__ ba,
    const float* __restrict__ gamma, const float* __restrict__ beta,
    const float* __restrict__ Wout, const float* __restrict__ bout,
    const int* __restrict__ rowptr, const int* __restrict__ cnt,
    const int* __restrict__ sortedSrc, float* __restrict__ out) {
  __shared__ float exs[32 * 8];    // per-chunk exp scores [edge][head]
  __shared__ u32   soff[32];       // per-chunk Hb row byte offsets
  __shared__ float sbase[8];       // si[n,h] + ba[h]
  __shared__ float accs[2][256];   // edge-parity partial acc per col
  __shared__ float dens[2][128];   // edge-parity partial den per col-pair
  __shared__ float lnorm[256];
  __shared__ float meanv[32];

  const int n = blockIdx.x;
  const int t = threadIdx.x;
  const int c = t & 127;           // column pair index (cols 2c, 2c+1)
  const int g = t >> 7;           // edge parity
  const int hh = c >> 4;          // head of cols 2c,2c+1
  const int start = rowptr[n];
  const int deg = cnt[n];
  if (t < 8) sbase[t] = si[n * HEADS + t] + ba[t];
  __syncthreads();

  const int i2c = t >> 3, h8 = t & 7;
  float acc0 = 0.f, acc1 = 0.f, den = 0.f;
  for (int base = 0; base < deg; base += 32) {
    const int m = min(32, deg - base);
    // Phase A: scores
    if (i2c < m) {
      int s = sortedSrc[start + base + i2c];
      float e = sbase[h8] + sj[s * HEADS + h8];
      e = (e >= 0.f) ? e : 0.2f * e;
      exs[i2c * 8 + h8] = __expf(e);
      if (h8 == 0) soff[i2c] = (u32)s * (HID * 2);
    }
    __syncthreads();
    // Phase B: gather-accumulate, 2 edges per iteration
    const int kmax = (m + 1) >> 1;
    for (int k = 0; k < kmax; k++) {
      int i2 = 2 * k + g;
      if (i2 < m) {
        u32 off = soff[i2];
        float exv = exs[i2 * 8 + hh];
        u32 hb2 = *(const u32*)((const char*)Hb + off + 4 * c);
        union { u32 u; float f; } lo, hi;
        lo.u = hb2 << 16;
        hi.u = hb2 & 0xFFFF0000u;
        acc0 += exv * lo.f;
        acc1 += exv * hi.f;
        den += exv;
      }
    }
    __syncthreads();
  }
  accs[g][c * 2]     = acc0;
  accs[g][c * 2 + 1] = acc1;
  dens[g][c] = den;
  __syncthreads();

  float accT = accs[0][t] + accs[1][t];
  float denT = dens[0][t >> 1] + dens[1][t >> 1];
  float hs = bf2f(Hb[n * HID + t]);
  float v = ((deg > 0) ? (accT / denT) : 0.f) + hs;
  v = (v > 0.f) ? v : expm1f(v);
  // LayerNorm over the 32 lanes of this head (head = t>>5)
  float sum = v, sq = v * v;
#pragma unroll
  for (int off = 16; off >= 1; off >>= 1) {
    sum += __shfl_xor(sum, off);
    sq  += __shfl_xor(sq, off);
  }
  float mu = sum * (1.f / 32.f);
  float var = sq * (1.f / 32.f) - mu * mu;
  float nv = (v - mu) * rsqrtf(var + 1e-5f) * gamma[t] + beta[t];
  lnorm[t] = nv;
  __syncthreads();
  if (t < 32) {
    float m2 = 0.f;
#pragma unroll
    for (int h2 = 0; h2 < HEADS; h2++) m2 += lnorm[h2 * 32 + t];
    meanv[t] = m2 * 0.125f;
  }
  __syncthreads();
  float y = bout[t];
#pragma unroll
  for (int k = 0; k < 32; k++) y += meanv[k] * Wout[k * HID + t];
  y = (y > 0.f) ? y : expm1f(y);
  out[n * HID + t] = y;
}

extern "C" void kernel_launch(void* const* d_in, const int* in_sizes, int n_in,
                              void* d_out, int out_size, void* d_ws, size_t ws_size,
                              hipStream_t stream) {
  const float* X     = (const float*)d_in[0];
  const int*   EI    = (const int*)d_in[1];
  const float* W     = (const float*)d_in[2];
  const float* bw    = (const float*)d_in[3];
  const float* A     = (const float*)d_in[4];
  const float* ba    = (const float*)d_in[5];
  const float* gamma = (const float*)d_in[6];
  const float* beta  = (const float*)d_in[7];
  const float* Wout  = (const float*)d_in[8];
  const float* bout  = (const float*)d_in[9];
  float* out = (float*)d_out;
  const int* tgt = EI;
  const int* src = EI + N_EDGES;

  char* ws = (char*)d_ws;
  size_t off = 0;
  auto alloc = [&](size_t bytes) -> void* {
    void* p = ws + off;
    off += bytes;
    off = (off + 255) & ~(size_t)255;
    return p;
  };
  u16*   Hb        = (u16*)  alloc((size_t)N_NODES * HID * 2);
  float* si        = (float*)alloc((size_t)N_NODES * HEADS * 4);
  float* sj        = (float*)alloc((size_t)N_NODES * HEADS * 4);
  int*   cnt       = (int*)  alloc((size_t)N_NODES * 4);
  int*   excl      = (int*)  alloc((size_t)N_NODES * 4);
  int*   bsum      = (int*)  alloc(256 * 4);
  int*   boff      = (int*)  alloc(256 * 4);
  int*   rowptr    = (int*)  alloc((size_t)N_NODES * 4);
  int*   cursor    = (int*)  alloc((size_t)N_NODES * 4);
  int*   sortedSrc = (int*)  alloc((size_t)N_EDGES * 4);

  hipMemsetAsync(cnt, 0, (size_t)N_NODES * 4, stream);
  k_hist<<<(N_EDGES + 255) / 256, 256, 0, stream>>>(tgt, cnt);
  k_scan1<<<196, 256, 0, stream>>>(cnt, excl, bsum);
  k_scan2<<<1, 256, 0, stream>>>(bsum, boff);
  k_scan3<<<196, 256, 0, stream>>>(excl, boff, rowptr, cursor);
  k_scatter<<<(N_EDGES + 255) / 256, 256, 0, stream>>>(tgt, src, cursor, sortedSrc);
  k_gemm<<<((N_NODES + 63) / 64) * 4, 256, 0, stream>>>(X, W, bw, Hb);
  k_attn<<<N_NODES, 256, 0, stream>>>(Hb, A, si, sj);
  k_fused<<<N_NODES, 256, 0, stream>>>(Hb, si, sj, ba, gamma, beta, Wout, bout,
                                       rowptr, cnt, sortedSrc, out);
}

// Round 4
// 630.891 us; speedup vs baseline: 1.3894x; 1.2020x over previous
//
#include <hip/hip_runtime.h>
#include <hip/hip_bf16.h>

#define N_NODES 50000
#define N_EDGES 1600000
#define HEADS 8
#define HD 32
#define FIN 256
#define HID 256

typedef unsigned short u16;
typedef unsigned int u32;

__device__ __forceinline__ float bf2f(u16 v) {
  union { u32 u; float f; } c; c.u = ((u32)v) << 16; return c.f;
}
__device__ __forceinline__ u16 f2bf(float f) {
  union { u32 u; float f; } c; c.f = f;
  u32 u = c.u;
  return (u16)((u + 0x7FFFu + ((u >> 16) & 1u)) >> 16);  // RNE
}

// ---------------- GEMM + fused attn projections --------------------------
// H[n][h*32+d] = X[n,:] @ W[h,:,d] + bw[h,d]; si/sj = per-head dots with A.
__global__ __launch_bounds__(256) void k_gemm(
    const float* __restrict__ X, const float* __restrict__ W,
    const float* __restrict__ bw, const float* __restrict__ A,
    u16* __restrict__ Hb, float* __restrict__ si, float* __restrict__ sj) {
  __shared__ float Xs[64][68];
  __shared__ float Ws[64][64];
  const int t = threadIdx.x;
  const int m0 = (blockIdx.x >> 2) * 64;
  const int n0 = (blockIdx.x & 3) * 64;
  const int tn = t & 15, ti = t >> 4;
  float acc[4][4] = {{0.f}};
  for (int k0 = 0; k0 < FIN; k0 += 64) {
#pragma unroll
    for (int r = 0; r < 16; r++) {
      int idx = (r << 8) + t;
      int kk = idx & 63, i = idx >> 6;
      int node = m0 + i;
      Xs[kk][i] = (node < N_NODES) ? X[node * FIN + k0 + kk] : 0.f;
    }
#pragma unroll
    for (int r = 0; r < 16; r++) {
      int idx = (r << 8) + t;
      int nn = idx & 63, kk = idx >> 6;
      int n = n0 + nn;
      int h = n >> 5, d = n & 31;
      Ws[kk][nn] = W[h * (FIN * HD) + (k0 + kk) * HD + d];
    }
    __syncthreads();
#pragma unroll 8
    for (int kk = 0; kk < 64; kk++) {
      const float4 xv = *(const float4*)&Xs[kk][ti << 2];
      const float4 wv = *(const float4*)&Ws[kk][tn << 2];
      acc[0][0] += xv.x * wv.x; acc[0][1] += xv.x * wv.y; acc[0][2] += xv.x * wv.z; acc[0][3] += xv.x * wv.w;
      acc[1][0] += xv.y * wv.x; acc[1][1] += xv.y * wv.y; acc[1][2] += xv.y * wv.z; acc[1][3] += xv.y * wv.w;
      acc[2][0] += xv.z * wv.x; acc[2][1] += xv.z * wv.y; acc[2][2] += xv.z * wv.z; acc[2][3] += xv.z * wv.w;
      acc[3][0] += xv.w * wv.x; acc[3][1] += xv.w * wv.y; acc[3][2] += xv.w * wv.z; acc[3][3] += xv.w * wv.w;
    }
    __syncthreads();
  }
  const int nbase = n0 + (tn << 2);
  // add bias in place
#pragma unroll
  for (int i = 0; i < 4; i++)
#pragma unroll
    for (int j = 0; j < 4; j++) acc[i][j] += bw[nbase + j];
  // store bf16 H
#pragma unroll
  for (int i = 0; i < 4; i++) {
    int node = m0 + (ti << 2) + i;
    if (node < N_NODES) {
      ushort4 o;
      o.x = f2bf(acc[i][0]); o.y = f2bf(acc[i][1]);
      o.z = f2bf(acc[i][2]); o.w = f2bf(acc[i][3]);
      *(ushort4*)&Hb[node * HID + nbase] = o;
    }
  }
  // fused attn projections: head of this thread's 4 cols
  const int head = nbase >> 5;
  const int d0 = nbase & 31;
  float a1[4], a2[4];
#pragma unroll
  for (int j = 0; j < 4; j++) {
    a1[j] = A[head * 64 + d0 + j];
    a2[j] = A[head * 64 + 32 + d0 + j];
  }
  float s1[4], s2[4];
#pragma unroll
  for (int i = 0; i < 4; i++) {
    s1[i] = acc[i][0] * a1[0] + acc[i][1] * a1[1] + acc[i][2] * a1[2] + acc[i][3] * a1[3];
    s2[i] = acc[i][0] * a2[0] + acc[i][1] * a2[1] + acc[i][2] * a2[2] + acc[i][3] * a2[3];
  }
#pragma unroll
  for (int off = 1; off <= 4; off <<= 1) {
#pragma unroll
    for (int i = 0; i < 4; i++) {
      s1[i] += __shfl_xor(s1[i], off);
      s2[i] += __shfl_xor(s2[i], off);
    }
  }
  if ((tn & 7) == 0) {
#pragma unroll
    for (int i = 0; i < 4; i++) {
      int node = m0 + (ti << 2) + i;
      if (node < N_NODES) {
        si[node * HEADS + head] = s1[i];
        sj[node * HEADS + head] = s2[i];
      }
    }
  }
}

// ---------------- counting sort of edges by target ----------------
__global__ void k_hist(const int* __restrict__ tgt, int* __restrict__ cnt) {
  int e = blockIdx.x * 256 + threadIdx.x;
  if (e < N_EDGES) atomicAdd(&cnt[tgt[e]], 1);
}

__global__ __launch_bounds__(256) void k_scan1(const int* __restrict__ cnt,
    int* __restrict__ excl, int* __restrict__ bsum) {
  __shared__ int s[256];
  const int t = threadIdx.x;
  const int i = blockIdx.x * 256 + t;
  int v = (i < N_NODES) ? cnt[i] : 0;
  s[t] = v;
  __syncthreads();
  int x = v;
  for (int off = 1; off < 256; off <<= 1) {
    int y = (t >= off) ? s[t - off] : 0;
    __syncthreads();
    x += y;
    s[t] = x;
    __syncthreads();
  }
  if (i < N_NODES) excl[i] = x - v;
  if (t == 255) bsum[blockIdx.x] = x;
}

__global__ __launch_bounds__(256) void k_scan2(const int* __restrict__ bsum,
                                               int* __restrict__ boff) {
  __shared__ int s[256];
  const int t = threadIdx.x;
  int v = (t < 196) ? bsum[t] : 0;
  s[t] = v;
  __syncthreads();
  int x = v;
  for (int off = 1; off < 256; off <<= 1) {
    int y = (t >= off) ? s[t - off] : 0;
    __syncthreads();
    x += y;
    s[t] = x;
    __syncthreads();
  }
  if (t < 196) boff[t] = x - v;
}

__global__ void k_scan3(const int* __restrict__ excl, const int* __restrict__ boff,
                        int* __restrict__ rowptr, int* __restrict__ cursor) {
  int i = blockIdx.x * 256 + threadIdx.x;
  if (i < N_NODES) {
    int v = excl[i] + boff[blockIdx.x];
    rowptr[i] = v;
    cursor[i] = v;
  }
}

__global__ void k_scatter(const int* __restrict__ tgt, const int* __restrict__ src,
                          int* __restrict__ cursor, int* __restrict__ sortedSrc) {
  int e = blockIdx.x * 256 + threadIdx.x;
  if (e < N_EDGES) {
    int tg = tgt[e];
    int pos = atomicAdd(&cursor[tg], 1);
    sortedSrc[pos] = src[e];
  }
}

// ---------------- fused: softmax-agg + skip + ELU + LN + head-mean + Wout + ELU
// Phase A: 32 edges x 8 heads -> exp scores in LDS (padded to 32: exv=0).
// Phase B: thread owns 8 cols (float4 = 8 bf16); 8 edge slots in parallel;
//          fixed trip count 4, unrolled -> 4 independent 16B gathers in flight.
__global__ __launch_bounds__(256) void k_fused(
    const u16* __restrict__ Hb, const float* __restrict__ si,
    const float* __restrict__ sj, const float* __restrict__ ba,
    const float* __restrict__ gamma, const float* __restrict__ beta,
    const float* __restrict__ Wout, const float* __restrict__ bout,
    const int* __restrict__ rowptr, const int* __restrict__ cnt,
    const int* __restrict__ sortedSrc, float* __restrict__ out) {
  __shared__ float exs[32 * 8];    // [edge][head], padded with zeros
  __shared__ u32   soff[32];       // Hb row byte offsets (0 for padding)
  __shared__ float sbase[8];       // si[n,h] + ba[h]
  __shared__ float accs[8][256];   // [edge-slot][col]
  __shared__ float dens[8][32];    // [edge-slot][col-group]
  __shared__ float lnorm[256];
  __shared__ float meanv[32];

  const int n = blockIdx.x;
  const int t = threadIdx.x;
  const int cg = t & 31;           // col group: cols cg*8 .. cg*8+7
  const int es = t >> 5;           // edge slot 0..7
  const int hh = cg >> 2;          // head of this col group
  const int start = rowptr[n];
  const int deg = cnt[n];
  if (t < 8) sbase[t] = si[n * HEADS + t] + ba[t];
  __syncthreads();

  const int i2c = t >> 3, h8 = t & 7;
  float acc[8] = {0.f, 0.f, 0.f, 0.f, 0.f, 0.f, 0.f, 0.f};
  float den = 0.f;
  for (int base = 0; base < deg; base += 32) {
    const int m = min(32, deg - base);
    // Phase A: scores (each exp computed once), pad to 32
    {
      float exv = 0.f;
      u32 off0 = 0;
      if (i2c < m) {
        int s = sortedSrc[start + base + i2c];
        float e = sbase[h8] + sj[s * HEADS + h8];
        e = (e >= 0.f) ? e : 0.2f * e;
        exv = __expf(e);
        off0 = (u32)s * (HID * 2);
      }
      exs[i2c * 8 + h8] = exv;
      if (h8 == 0) soff[i2c] = off0;
    }
    __syncthreads();
    // Phase B: 4 unrolled iterations; padding rows contribute exactly 0
#pragma unroll
    for (int k = 0; k < 4; k++) {
      int i2 = k * 8 + es;
      u32 off = soff[i2];
      float exv = exs[i2 * 8 + hh];
      float4 hb4 = *(const float4*)((const char*)Hb + off + 16 * cg);
      const u32* hw = (const u32*)&hb4;
#pragma unroll
      for (int d = 0; d < 4; d++) {
        union { u32 u; float f; } lo, hi;
        lo.u = hw[d] << 16;
        hi.u = hw[d] & 0xFFFF0000u;
        acc[2 * d]     += exv * lo.f;
        acc[2 * d + 1] += exv * hi.f;
      }
      den += exv;
    }
    __syncthreads();
  }
#pragma unroll
  for (int j = 0; j < 8; j++) accs[es][cg * 8 + j] = acc[j];
  dens[es][cg] = den;
  __syncthreads();

  float accT = 0.f, denT = 0.f;
#pragma unroll
  for (int e2 = 0; e2 < 8; e2++) {
    accT += accs[e2][t];
    denT += dens[e2][t >> 3];
  }
  float hs = bf2f(Hb[n * HID + t]);
  float v = ((deg > 0) ? (accT / denT) : 0.f) + hs;
  v = (v > 0.f) ? v : expm1f(v);
  // LayerNorm over the 32 lanes of this head (head = t>>5)
  float sum = v, sq = v * v;
#pragma unroll
  for (int off = 16; off >= 1; off >>= 1) {
    sum += __shfl_xor(sum, off);
    sq  += __shfl_xor(sq, off);
  }
  float mu = sum * (1.f / 32.f);
  float var = sq * (1.f / 32.f) - mu * mu;
  float nv = (v - mu) * rsqrtf(var + 1e-5f) * gamma[t] + beta[t];
  lnorm[t] = nv;
  __syncthreads();
  if (t < 32) {
    float m2 = 0.f;
#pragma unroll
    for (int h2 = 0; h2 < HEADS; h2++) m2 += lnorm[h2 * 32 + t];
    meanv[t] = m2 * 0.125f;
  }
  __syncthreads();
  float y = bout[t];
#pragma unroll
  for (int k = 0; k < 32; k++) y += meanv[k] * Wout[k * HID + t];
  y = (y > 0.f) ? y : expm1f(y);
  out[n * HID + t] = y;
}

extern "C" void kernel_launch(void* const* d_in, const int* in_sizes, int n_in,
                              void* d_out, int out_size, void* d_ws, size_t ws_size,
                              hipStream_t stream) {
  const float* X     = (const float*)d_in[0];
  const int*   EI    = (const int*)d_in[1];
  const float* W     = (const float*)d_in[2];
  const float* bw    = (const float*)d_in[3];
  const float* A     = (const float*)d_in[4];
  const float* ba    = (const float*)d_in[5];
  const float* gamma = (const float*)d_in[6];
  const float* beta  = (const float*)d_in[7];
  const float* Wout  = (const float*)d_in[8];
  const float* bout  = (const float*)d_in[9];
  float* out = (float*)d_out;
  const int* tgt = EI;
  const int* src = EI + N_EDGES;

  char* ws = (char*)d_ws;
  size_t off = 0;
  auto alloc = [&](size_t bytes) -> void* {
    void* p = ws + off;
    off += bytes;
    off = (off + 255) & ~(size_t)255;
    return p;
  };
  u16*   Hb        = (u16*)  alloc((size_t)N_NODES * HID * 2);
  float* si        = (float*)alloc((size_t)N_NODES * HEADS * 4);
  float* sj        = (float*)alloc((size_t)N_NODES * HEADS * 4);
  int*   cnt       = (int*)  alloc((size_t)N_NODES * 4);
  int*   excl      = (int*)  alloc((size_t)N_NODES * 4);
  int*   bsum      = (int*)  alloc(256 * 4);
  int*   boff      = (int*)  alloc(256 * 4);
  int*   rowptr    = (int*)  alloc((size_t)N_NODES * 4);
  int*   cursor    = (int*)  alloc((size_t)N_NODES * 4);
  int*   sortedSrc = (int*)  alloc((size_t)N_EDGES * 4);

  hipMemsetAsync(cnt, 0, (size_t)N_NODES * 4, stream);
  k_hist<<<(N_EDGES + 255) / 256, 256, 0, stream>>>(tgt, cnt);
  k_scan1<<<196, 256, 0, stream>>>(cnt, excl, bsum);
  k_scan2<<<1, 256, 0, stream>>>(bsum, boff);
  k_scan3<<<196, 256, 0, stream>>>(excl, boff, rowptr, cursor);
  k_scatter<<<(N_EDGES + 255) / 256, 256, 0, stream>>>(tgt, src, cursor, sortedSrc);
  k_gemm<<<((N_NODES + 63) / 64) * 4, 256, 0, stream>>>(X, W, bw, A, Hb, si, sj);
  k_fused<<<N_NODES, 256, 0, stream>>>(Hb, si, sj, ba, gamma, beta, Wout, bout,
                                       rowptr, cnt, sortedSrc, out);
}

// Round 5
// 526.707 us; speedup vs baseline: 1.6643x; 1.1978x over previous
//
#include <hip/hip_runtime.h>
#include <hip/hip_bf16.h>

#define N_NODES 50000
#define N_EDGES 1600000
#define HEADS 8
#define HD 32
#define FIN 256
#define HID 256

typedef unsigned short u16;
typedef unsigned int u32;

typedef short s8v __attribute__((ext_vector_type(8)));   // 8 bf16 (4 VGPRs)
typedef float f4v __attribute__((ext_vector_type(4)));   // 4 fp32 acc

__device__ __forceinline__ float bf2f(u16 v) {
  union { u32 u; float f; } c; c.u = ((u32)v) << 16; return c.f;
}
__device__ __forceinline__ u16 f2bf(float f) {
  union { u32 u; float f; } c; c.f = f;
  u32 u = c.u;
  return (u16)((u + 0x7FFFu + ((u >> 16) & 1u)) >> 16);  // RNE
}
__device__ __forceinline__ u32 pk2(float lo, float hi) {
  return (u32)f2bf(lo) | ((u32)f2bf(hi) << 16);
}

// ---------------- MFMA GEMM + fused attn projections ------------------------
// H[n][h*32+d] = X[n,:] @ W[h,:,d] + bw[h,d], stored bf16.
// Block: 256 thr (2x2 waves), tile 128 nodes x 128 cols, K-tiles of 32.
// mfma_f32_16x16x32_bf16: A[m=lane&15][k=quad*8+j], B[k=quad*8+j][n=lane&15],
// C/D col=lane&15, row=quad*4+reg  (HW-verified layouts).
__global__ __launch_bounds__(256) void k_gemm(
    const float* __restrict__ X, const float* __restrict__ W,
    const float* __restrict__ bw, const float* __restrict__ A,
    u16* __restrict__ Hb, float* __restrict__ si, float* __restrict__ sj) {
  __shared__ __align__(16) u16 Xs[128 * 40];  // [row][k] stride 40 (32+8 pad: 2-way only)
  __shared__ __align__(16) u16 Wt[128 * 40];  // [col][k] stride 40

  const int t = threadIdx.x;
  const int m0 = (blockIdx.x >> 1) * 128;
  const int n0 = (blockIdx.x & 1) * 128;
  const int w = t >> 6;
  const int lane = t & 63;
  const int l15 = lane & 15;
  const int quad = lane >> 4;
  const int wm = (w >> 1) * 64;   // wave row offset in block tile
  const int wn = (w & 1) * 64;    // wave col offset in block tile

  f4v acc[4][4];
#pragma unroll
  for (int i = 0; i < 4; i++)
#pragma unroll
    for (int j = 0; j < 4; j++) acc[i][j] = (f4v){0.f, 0.f, 0.f, 0.f};

  // W staging assignment (constant over k-loop)
  const int nl = t & 127;          // local col
  const int half = t >> 7;         // k half (0/1): kk = half*16 + i
  const int gn = n0 + nl;
  const int gh = gn >> 5, gd = gn & 31;

  for (int k0 = 0; k0 < FIN; k0 += 32) {
    // stage X tile: 128 rows x 32 k (fp32 -> bf16)
#pragma unroll
    for (int p = 0; p < 4; p++) {
      int row = p * 32 + (t >> 3);
      int f4 = t & 7;
      int node = m0 + row;
      float4 xv = make_float4(0.f, 0.f, 0.f, 0.f);
      if (node < N_NODES) xv = *(const float4*)&X[node * FIN + k0 + f4 * 4];
      u32* dst = (u32*)&Xs[row * 40 + f4 * 4];
      dst[0] = pk2(xv.x, xv.y);
      dst[1] = pk2(xv.z, xv.w);
    }
    // stage W tile transposed: Wt[col][kk] = W[h][k0+kk][d]
    {
      const float* wp = W + gh * (FIN * HD) + (k0 + half * 16) * HD + gd;
#pragma unroll
      for (int j = 0; j < 8; j++) {
        float lo = wp[(2 * j) * HD];
        float hi = wp[(2 * j + 1) * HD];
        *(u32*)&Wt[nl * 40 + half * 16 + 2 * j] = pk2(lo, hi);
      }
    }
    __syncthreads();
    s8v af[4], bf[4];
#pragma unroll
    for (int mi = 0; mi < 4; mi++)
      af[mi] = *(const s8v*)&Xs[(wm + mi * 16 + l15) * 40 + quad * 8];
#pragma unroll
    for (int ni = 0; ni < 4; ni++)
      bf[ni] = *(const s8v*)&Wt[(wn + ni * 16 + l15) * 40 + quad * 8];
#pragma unroll
    for (int mi = 0; mi < 4; mi++)
#pragma unroll
      for (int ni = 0; ni < 4; ni++)
        acc[mi][ni] = __builtin_amdgcn_mfma_f32_16x16x32_bf16(af[mi], bf[ni], acc[mi][ni], 0, 0, 0);
    __syncthreads();
  }

  // epilogue: bias, store bf16 H, fused si/sj
  const int head0 = (n0 + wn) >> 5;
  const int head1 = head0 + 1;
  float c1a0 = A[head0 * 64 + l15],      c1a1 = A[head0 * 64 + 16 + l15];
  float c2a0 = A[head0 * 64 + 32 + l15], c2a1 = A[head0 * 64 + 48 + l15];
  float c1b0 = A[head1 * 64 + l15],      c1b1 = A[head1 * 64 + 16 + l15];
  float c2b0 = A[head1 * 64 + 32 + l15], c2b1 = A[head1 * 64 + 48 + l15];

#pragma unroll
  for (int mi = 0; mi < 4; mi++) {
    // bias (per-col)
#pragma unroll
    for (int ni = 0; ni < 4; ni++) {
      float b = bw[n0 + wn + ni * 16 + l15];
#pragma unroll
      for (int r = 0; r < 4; r++) acc[mi][ni][r] += b;
    }
    // store H
    const int rbase = m0 + wm + mi * 16 + quad * 4;
#pragma unroll
    for (int r = 0; r < 4; r++) {
      int node = rbase + r;
      if (node < N_NODES) {
#pragma unroll
        for (int ni = 0; ni < 4; ni++) {
          int col = n0 + wn + ni * 16 + l15;
          Hb[node * HID + col] = f2bf(acc[mi][ni][r]);
        }
      }
    }
    // si/sj: dot over head dims via intra-quad shuffle reduce
    float s1a[4], s2a[4], s1b[4], s2b[4];
#pragma unroll
    for (int r = 0; r < 4; r++) {
      s1a[r] = acc[mi][0][r] * c1a0 + acc[mi][1][r] * c1a1;
      s2a[r] = acc[mi][0][r] * c2a0 + acc[mi][1][r] * c2a1;
      s1b[r] = acc[mi][2][r] * c1b0 + acc[mi][3][r] * c1b1;
      s2b[r] = acc[mi][2][r] * c2b0 + acc[mi][3][r] * c2b1;
    }
#pragma unroll
    for (int off = 1; off <= 8; off <<= 1) {
#pragma unroll
      for (int r = 0; r < 4; r++) {
        s1a[r] += __shfl_xor(s1a[r], off);
        s2a[r] += __shfl_xor(s2a[r], off);
        s1b[r] += __shfl_xor(s1b[r], off);
        s2b[r] += __shfl_xor(s2b[r], off);
      }
    }
    if (l15 == 0) {
#pragma unroll
      for (int r = 0; r < 4; r++) {
        int node = rbase + r;
        if (node < N_NODES) {
          si[node * HEADS + head0] = s1a[r];
          sj[node * HEADS + head0] = s2a[r];
          si[node * HEADS + head1] = s1b[r];
          sj[node * HEADS + head1] = s2b[r];
        }
      }
    }
  }
}

// ---------------- counting sort of edges by target ----------------
__global__ void k_hist(const int* __restrict__ tgt, int* __restrict__ cnt) {
  int e = blockIdx.x * 256 + threadIdx.x;
  if (e < N_EDGES) atomicAdd(&cnt[tgt[e]], 1);
}

__global__ __launch_bounds__(256) void k_scan1(const int* __restrict__ cnt,
    int* __restrict__ excl, int* __restrict__ bsum) {
  __shared__ int s[256];
  const int t = threadIdx.x;
  const int i = blockIdx.x * 256 + t;
  int v = (i < N_NODES) ? cnt[i] : 0;
  s[t] = v;
  __syncthreads();
  int x = v;
  for (int off = 1; off < 256; off <<= 1) {
    int y = (t >= off) ? s[t - off] : 0;
    __syncthreads();
    x += y;
    s[t] = x;
    __syncthreads();
  }
  if (i < N_NODES) excl[i] = x - v;
  if (t == 255) bsum[blockIdx.x] = x;
}

__global__ __launch_bounds__(256) void k_scan2(const int* __restrict__ bsum,
                                               int* __restrict__ boff) {
  __shared__ int s[256];
  const int t = threadIdx.x;
  int v = (t < 196) ? bsum[t] : 0;
  s[t] = v;
  __syncthreads();
  int x = v;
  for (int off = 1; off < 256; off <<= 1) {
    int y = (t >= off) ? s[t - off] : 0;
    __syncthreads();
    x += y;
    s[t] = x;
    __syncthreads();
  }
  if (t < 196) boff[t] = x - v;
}

__global__ void k_scan3(const int* __restrict__ excl, const int* __restrict__ boff,
                        int* __restrict__ rowptr, int* __restrict__ cursor) {
  int i = blockIdx.x * 256 + threadIdx.x;
  if (i < N_NODES) {
    int v = excl[i] + boff[blockIdx.x];
    rowptr[i] = v;
    cursor[i] = v;
  }
}

__global__ void k_scatter(const int* __restrict__ tgt, const int* __restrict__ src,
                          int* __restrict__ cursor, int* __restrict__ sortedSrc) {
  int e = blockIdx.x * 256 + threadIdx.x;
  if (e < N_EDGES) {
    int tg = tgt[e];
    int pos = atomicAdd(&cursor[tg], 1);
    sortedSrc[pos] = src[e];
  }
}

// ---------------- fused: softmax-agg + skip + ELU + LN + head-mean + Wout + ELU
__global__ __launch_bounds__(256) void k_fused(
    const u16* __restrict__ Hb, const float* __restrict__ si,
    const float* __restrict__ sj, const float* __restrict__ ba,
    const float* __restrict__ gamma, const float* __restrict__ beta,
    const float* __restrict__ Wout, const float* __restrict__ bout,
    const int* __restrict__ rowptr, const int* __restrict__ cnt,
    const int* __restrict__ sortedSrc, float* __restrict__ out) {
  __shared__ float exs[32 * 8];    // [edge][head], padded with zeros
  __shared__ u32   soff[32];       // Hb row byte offsets (0 for padding)
  __shared__ float sbase[8];       // si[n,h] + ba[h]
  __shared__ float accs[8][256];   // [edge-slot][col]
  __shared__ float dens[8][32];    // [edge-slot][col-group]
  __shared__ float lnorm[256];
  __shared__ float meanv[32];

  const int n = blockIdx.x;
  const int t = threadIdx.x;
  const int cg = t & 31;           // col group: cols cg*8 .. cg*8+7
  const int es = t >> 5;           // edge slot 0..7
  const int hh = cg >> 2;          // head of this col group
  const int start = rowptr[n];
  const int deg = cnt[n];
  if (t < 8) sbase[t] = si[n * HEADS + t] + ba[t];
  __syncthreads();

  const int i2c = t >> 3, h8 = t & 7;
  float acc[8] = {0.f, 0.f, 0.f, 0.f, 0.f, 0.f, 0.f, 0.f};
  float den = 0.f;
  for (int base = 0; base < deg; base += 32) {
    const int m = min(32, deg - base);
    {
      float exv = 0.f;
      u32 off0 = 0;
      if (i2c < m) {
        int s = sortedSrc[start + base + i2c];
        float e = sbase[h8] + sj[s * HEADS + h8];
        e = (e >= 0.f) ? e : 0.2f * e;
        exv = __expf(e);
        off0 = (u32)s * (HID * 2);
      }
      exs[i2c * 8 + h8] = exv;
      if (h8 == 0) soff[i2c] = off0;
    }
    __syncthreads();
#pragma unroll
    for (int k = 0; k < 4; k++) {
      int i2 = k * 8 + es;
      u32 off = soff[i2];
      float exv = exs[i2 * 8 + hh];
      float4 hb4 = *(const float4*)((const char*)Hb + off + 16 * cg);
      const u32* hw = (const u32*)&hb4;
#pragma unroll
      for (int d = 0; d < 4; d++) {
        union { u32 u; float f; } lo, hi;
        lo.u = hw[d] << 16;
        hi.u = hw[d] & 0xFFFF0000u;
        acc[2 * d]     += exv * lo.f;
        acc[2 * d + 1] += exv * hi.f;
      }
      den += exv;
    }
    __syncthreads();
  }
#pragma unroll
  for (int j = 0; j < 8; j++) accs[es][cg * 8 + j] = acc[j];
  dens[es][cg] = den;
  __syncthreads();

  float accT = 0.f, denT = 0.f;
#pragma unroll
  for (int e2 = 0; e2 < 8; e2++) {
    accT += accs[e2][t];
    denT += dens[e2][t >> 3];
  }
  float hs = bf2f(Hb[n * HID + t]);
  float v = ((deg > 0) ? (accT / denT) : 0.f) + hs;
  v = (v > 0.f) ? v : expm1f(v);
  float sum = v, sq = v * v;
#pragma unroll
  for (int off = 16; off >= 1; off >>= 1) {
    sum += __shfl_xor(sum, off);
    sq  += __shfl_xor(sq, off);
  }
  float mu = sum * (1.f / 32.f);
  float var = sq * (1.f / 32.f) - mu * mu;
  float nv = (v - mu) * rsqrtf(var + 1e-5f) * gamma[t] + beta[t];
  lnorm[t] = nv;
  __syncthreads();
  if (t < 32) {
    float m2 = 0.f;
#pragma unroll
    for (int h2 = 0; h2 < HEADS; h2++) m2 += lnorm[h2 * 32 + t];
    meanv[t] = m2 * 0.125f;
  }
  __syncthreads();
  float y = bout[t];
#pragma unroll
  for (int k = 0; k < 32; k++) y += meanv[k] * Wout[k * HID + t];
  y = (y > 0.f) ? y : expm1f(y);
  out[n * HID + t] = y;
}

extern "C" void kernel_launch(void* const* d_in, const int* in_sizes, int n_in,
                              void* d_out, int out_size, void* d_ws, size_t ws_size,
                              hipStream_t stream) {
  const float* X     = (const float*)d_in[0];
  const int*   EI    = (const int*)d_in[1];
  const float* W     = (const float*)d_in[2];
  const float* bw    = (const float*)d_in[3];
  const float* A     = (const float*)d_in[4];
  const float* ba    = (const float*)d_in[5];
  const float* gamma = (const float*)d_in[6];
  const float* beta  = (const float*)d_in[7];
  const float* Wout  = (const float*)d_in[8];
  const float* bout  = (const float*)d_in[9];
  float* out = (float*)d_out;
  const int* tgt = EI;
  const int* src = EI + N_EDGES;

  char* ws = (char*)d_ws;
  size_t off = 0;
  auto alloc = [&](size_t bytes) -> void* {
    void* p = ws + off;
    off += bytes;
    off = (off + 255) & ~(size_t)255;
    return p;
  };
  u16*   Hb        = (u16*)  alloc((size_t)N_NODES * HID * 2);
  float* si        = (float*)alloc((size_t)N_NODES * HEADS * 4);
  float* sj        = (float*)alloc((size_t)N_NODES * HEADS * 4);
  int*   cnt       = (int*)  alloc((size_t)N_NODES * 4);
  int*   excl      = (int*)  alloc((size_t)N_NODES * 4);
  int*   bsum      = (int*)  alloc(256 * 4);
  int*   boff      = (int*)  alloc(256 * 4);
  int*   rowptr    = (int*)  alloc((size_t)N_NODES * 4);
  int*   cursor    = (int*)  alloc((size_t)N_NODES * 4);
  int*   sortedSrc = (int*)  alloc((size_t)N_EDGES * 4);

  hipMemsetAsync(cnt, 0, (size_t)N_NODES * 4, stream);
  k_hist<<<(N_EDGES + 255) / 256, 256, 0, stream>>>(tgt, cnt);
  k_scan1<<<196, 256, 0, stream>>>(cnt, excl, bsum);
  k_scan2<<<1, 256, 0, stream>>>(bsum, boff);
  k_scan3<<<196, 256, 0, stream>>>(excl, boff, rowptr, cursor);
  k_scatter<<<(N_EDGES + 255) / 256, 256, 0, stream>>>(tgt, src, cursor, sortedSrc);
  k_gemm<<<((N_NODES + 127) / 128) * 2, 256, 0, stream>>>(X, W, bw, A, Hb, si, sj);
  k_fused<<<N_NODES, 256, 0, stream>>>(Hb, si, sj, ba, gamma, beta, Wout, bout,
                                       rowptr, cnt, sortedSrc, out);
}